// Round 7
// baseline (103.248 us; speedup 1.0000x reference)
//
#include <hip/hip_runtime.h>
#include <stdint.h>

typedef short short8 __attribute__((ext_vector_type(8)));
typedef short short4v __attribute__((ext_vector_type(4)));
typedef float f32x4 __attribute__((ext_vector_type(4)));
typedef unsigned int u32x2 __attribute__((ext_vector_type(2)));
typedef unsigned int u32x4 __attribute__((ext_vector_type(4)));
typedef unsigned short u16;
typedef unsigned int u32;

#define T_ 2048
#define QK_SCALE 0.180336878f   // 0.125 * log2(e): softmax in log2 domain

__device__ inline u16 f2bf(float f) {
  unsigned u = __builtin_bit_cast(unsigned, f);
  u += 0x7fffu + ((u >> 16) & 1u);   // RNE; inputs finite
  return (u16)(u >> 16);
}

__device__ inline u32 cvt_pk_bf16(float lo, float hi) {
  u32 r;
  asm("v_cvt_pk_bf16_f32 %0, %1, %2" : "=v"(r) : "v"(lo), "v"(hi));
  return r;
}

__device__ inline f32x4 mfma_bf16(short8 a, short8 b, f32x4 c) {
  return __builtin_amdgcn_mfma_f32_16x16x32_bf16(a, b, c, 0, 0, 0);
}

// async global->LDS, 16B per lane; lds base must be wave-uniform
__device__ inline void gload16(const u16* g, u16* l) {
  __builtin_amdgcn_global_load_lds(
      (const __attribute__((address_space(1))) void*)g,
      (__attribute__((address_space(3))) void*)l, 16, 0, 0);
}

// ---------------- fused prep: convert x + transpose-convert both weights ----------------

__device__ inline void tile_transpose(const float* __restrict__ W, u16* __restrict__ Wt,
                                      int R, int Ccols, int c0, int r0, int t,
                                      float (*tile)[33]) {
  int tr = t >> 3, tc = (t & 7) * 4;
  float4 v = *(const float4*)&W[(size_t)(r0 + tr) * Ccols + c0 + tc];
  tile[tr][tc + 0] = v.x; tile[tr][tc + 1] = v.y;
  tile[tr][tc + 2] = v.z; tile[tr][tc + 3] = v.w;
  __syncthreads();
  short4v o;
#pragma unroll
  for (int i = 0; i < 4; ++i) o[i] = (short)f2bf(tile[tc + i][tr]);
  *(short4v*)&Wt[(size_t)(c0 + tr) * R + r0 + tc] = o;
}

__global__ __launch_bounds__(256) void prep_kernel(const float* __restrict__ x,
                                                   const float* __restrict__ Wqkv,
                                                   const float* __restrict__ Wproj,
                                                   u16* __restrict__ xb,
                                                   u16* __restrict__ wqkvT,
                                                   u16* __restrict__ wprojT) {
  __shared__ float tile[32][33];
  int bid = blockIdx.x, t = threadIdx.x;
  if (bid < 3072) {
    int i = (bid * 256 + t) * 4;
    float4 v = *(const float4*)&x[i];
    short4v o;
    o[0] = (short)f2bf(v.x); o[1] = (short)f2bf(v.y);
    o[2] = (short)f2bf(v.z); o[3] = (short)f2bf(v.w);
    *(short4v*)&xb[i] = o;
  } else if (bid < 3072 + 1728) {
    int t2 = bid - 3072;
    tile_transpose(Wqkv, wqkvT, 768, 2304, (t2 % 72) * 32, (t2 / 72) * 32, t, tile);
  } else {
    int t3 = bid - 4800;
    tile_transpose(Wproj, wprojT, 768, 768, (t3 % 24) * 32, (t3 / 24) * 32, t, tile);
  }
}

// ---------------- MTILE x 128 GEMM (gload_lds w16 + XOR swizzle + XCD chunking) ----------------
// A [M][768] bf16, Bt [N][768] bf16 (n-major). 4 waves.
// MODE 0 (MTILE=128): qkv epilogue (q/k direct, V^T via LDS transpose);
// MODE 1 (MTILE=64):  proj epilogue (fp32 out + bias), 2x grid occupancy.

template <int MODE, int MTILE>
__global__ __launch_bounds__(256) void gemm_kernel(const u16* __restrict__ A,
                                                   const u16* __restrict__ Bt,
                                                   const float* __restrict__ bias,
                                                   u16* __restrict__ qb,
                                                   u16* __restrict__ kb,
                                                   u16* __restrict__ vpb,
                                                   float* __restrict__ out) {
  constexpr int MF = MTILE / 32;            // m-fragments per wave
  __shared__ u16 S[MTILE * 64 + 8192];      // As | Bs
  u16* As = S;
  u16* Bs = S + MTILE * 64;
  int tid = threadIdx.x, w = tid >> 6, l = tid & 63, lg = l >> 4, lr = l & 15;
  // XCD-chunked bijective swizzle: consecutive logical ids (same A panel) on one XCD
  int nwg = gridDim.x * gridDim.y;
  int hw = blockIdx.y * gridDim.x + blockIdx.x;
  int logical = (hw & 7) * (nwg >> 3) + (hw >> 3);
  int n0 = (logical % gridDim.x) * 128, m0 = (logical / gridDim.x) * MTILE;
  int wm = (w >> 1) * (MTILE / 2), wn = (w & 1) * 64;
  f32x4 acc[MF][4] = {};
  int rsub = l >> 3;
  int sc = ((l & 7) ^ rsub) * 8;
  for (int kt = 0; kt < 12; ++kt) {
    int k0 = kt * 64;
    __syncthreads();
#pragma unroll
    for (int j = 0; j < MF; ++j) {
      int row = w * (MTILE / 4) + j * 8 + rsub;
      gload16(&A[(size_t)(m0 + row) * 768 + k0 + sc], &As[(w * MF + j) * 512]);
    }
#pragma unroll
    for (int j = 0; j < 4; ++j) {
      int row = w * 32 + j * 8 + rsub;
      gload16(&Bt[(size_t)(n0 + row) * 768 + k0 + sc], &Bs[(w * 4 + j) * 512]);
    }
    __syncthreads();
    short8 a[MF][2], b[4][2];
#pragma unroll
    for (int h = 0; h < 2; ++h) {
#pragma unroll
      for (int mf = 0; mf < MF; ++mf) {
        int cw = ((h * 4 + lg) ^ (lr & 7)) * 8;
        a[mf][h] = *(const short8*)&As[(wm + mf * 16 + lr) * 64 + cw];
      }
#pragma unroll
      for (int nf = 0; nf < 4; ++nf) {
        int cw = ((h * 4 + lg) ^ (lr & 7)) * 8;
        b[nf][h] = *(const short8*)&Bs[(wn + nf * 16 + lr) * 64 + cw];
      }
    }
#pragma unroll
    for (int h = 0; h < 2; ++h)
#pragma unroll
      for (int mf = 0; mf < MF; ++mf)
#pragma unroll
        for (int nf = 0; nf < 4; ++nf)
          acc[mf][nf] = mfma_bf16(a[mf][h], b[nf][h], acc[mf][nf]);
  }

  if constexpr (MODE == 0) {
    int sec = (n0 >= 1536) ? 2 : (n0 >= 768 ? 1 : 0);
    int ncol0 = n0 - sec * 768;
    if (sec < 2) {
#pragma unroll
      for (int nf = 0; nf < 4; ++nf) {
        int nn = wn + nf * 16 + lr;
        float bv = bias[n0 + nn];
        int c = ncol0 + nn;
        int hh = c >> 6, d = c & 63;
#pragma unroll
        for (int mf = 0; mf < MF; ++mf)
#pragma unroll
          for (int rr = 0; rr < 4; ++rr) {
            int m = m0 + wm + mf * 16 + 4 * lg + rr;
            int bb = m >> 11, tt = m & 2047;
            int bh = bb * 12 + hh;
            float v = acc[mf][nf][rr] + bv;
            if (sec == 0) qb[((size_t)bh * T_ + tt) * 64 + d] = f2bf(v * QK_SCALE);
            else          kb[((size_t)bh * T_ + tt) * 64 + d] = f2bf(v);
          }
      }
    } else {
      // V^T: transpose in LDS (p5 key-permutation folded into column), coalesced rows out.
      __syncthreads();   // done reading As/Bs
#pragma unroll
      for (int nf = 0; nf < 4; ++nf) {
        int row = wn + nf * 16 + lr;          // n-index within block (d dim)
        float bv = bias[n0 + row];
        int swz = (row & 7) << 3;             // u16-granule XOR (16B chunks)
#pragma unroll
        for (int mf = 0; mf < MF; ++mf) {
          // permuted m-col: p5 = 8*lg + 4*(mf&1) + rr within each 32-group
          int pcol0 = wm + (mf >> 1) * 32 + 8 * lg + 4 * (mf & 1);
          u32x2 pk;
          pk[0] = cvt_pk_bf16(acc[mf][nf][0] + bv, acc[mf][nf][1] + bv);
          pk[1] = cvt_pk_bf16(acc[mf][nf][2] + bv, acc[mf][nf][3] + bv);
          *(u32x2*)&S[row * 128 + (pcol0 ^ swz)] = pk;
        }
      }
      __syncthreads();
      int rowo = tid >> 1, half = tid & 1;
      int c = ncol0 + rowo;
      int d = c & 63, hh = c >> 6;
      int bh = (m0 >> 11) * 12 + hh;
      u16* dst = vpb + ((size_t)bh * 64 + d) * T_ + (m0 & 2047) + half * 64;
      int swzo = (rowo & 7) << 3;
#pragma unroll
      for (int i = 0; i < 8; ++i) {
        uint4 v = *(const uint4*)&S[rowo * 128 + ((half * 64 + i * 8) ^ swzo)];
        *(uint4*)&dst[i * 8] = v;
      }
    }
  } else {
#pragma unroll
    for (int nf = 0; nf < 4; ++nf) {
      int n = n0 + wn + nf * 16 + lr;
      float bv = bias[n];
#pragma unroll
      for (int mf = 0; mf < MF; ++mf)
#pragma unroll
        for (int rr = 0; rr < 4; ++rr) {
          int m = m0 + wm + mf * 16 + 4 * lg + rr;
          out[(size_t)m * 768 + n] = acc[mf][nf][rr] + bv;
        }
    }
  }
}

// ---------------- flash attention (no-max softmax, counted-vmcnt pipeline) ----------------
// Q,K: [BH][T][64] bf16 (Q pre-scaled by 0.125*log2e), Vp: [BH][64][T] bf16
// (key-permuted), O: [B*T][768] bf16. 4 waves x 16 q = 64-q blocks; 768 blocks.
// Pipeline: issue loads(t+1) -> vmcnt(4) [tile t landed, t+1 in flight] ->
// s_barrier -> compute(t) -> s_barrier. No vmcnt(0) drain in the loop (T3/T4).

__global__ __launch_bounds__(256) void attn_kernel(const u16* __restrict__ Q,
                                                   const u16* __restrict__ K,
                                                   const u16* __restrict__ Vp,
                                                   u16* __restrict__ O) {
  __shared__ u16 sh[16384];  // K dbuf 2x4096, V dbuf 2x4096 (swizzled linear)
  int tid = threadIdx.x;
  int w = tid >> 6, l = tid & 63, lg = l >> 4, lr = l & 15;
  // XCD-chunked: 96 consecutive logical blocks (3 whole heads) per XCD
  int hw = blockIdx.x;
  int logical = (hw & 7) * 96 + (hw >> 3);
  int head = logical >> 5;             // 24 heads x 32 q-blocks
  int qblk = 31 - (logical & 31);      // big-work blocks first within chunk
  int b = head / 12, h = head % 12;
  int q0 = qblk * 64;
  int q0w = q0 + w * 16;               // this wave's 16 q-rows
  const u16* Qb = Q + (size_t)head * T_ * 64;
  const u16* Kb = K + (size_t)head * T_ * 64;
  const u16* Vb = Vp + (size_t)head * 64 * T_;

  short8 qf0 = *(const short8*)&Qb[(size_t)(q0w + lr) * 64 + 8 * lg];
  short8 qf1 = *(const short8*)&Qb[(size_t)(q0w + lr) * 64 + 32 + 8 * lg];

  f32x4 ao[4] = {};
  float lrow = 0.f;
  int rsub = l >> 3;
  int scs = ((l & 7) ^ rsub) * 8;
  const int nt = qblk + 1;             // 64-key tiles covering keys <= q0+63

  // prologue: stage tile 0 (4 waves x 2 issues cover 64 rows of K and V)
#pragma unroll
  for (int j = 0; j < 2; ++j) {
    int ci = w * 2 + j;
    int row = ci * 8 + rsub;
    gload16(&Kb[(size_t)row * 64 + scs], &sh[ci * 512]);
    gload16(&Vb[(size_t)row * T_ + scs], &sh[8192 + ci * 512]);
  }

  for (int t = 0; t < nt; ++t) {
    int cur = t & 1;
    int k0 = t * 64;
    if (t + 1 < nt) {
      int k1 = k0 + 64;
#pragma unroll
      for (int j = 0; j < 2; ++j) {
        int ci = w * 2 + j;
        int row = ci * 8 + rsub;
        gload16(&Kb[(size_t)(k1 + row) * 64 + scs], &sh[(cur ^ 1) * 4096 + ci * 512]);
        gload16(&Vb[(size_t)row * T_ + k1 + scs], &sh[8192 + (cur ^ 1) * 4096 + ci * 512]);
      }
      asm volatile("s_waitcnt vmcnt(4)" ::: "memory");  // tile t landed; t+1 in flight
    } else {
      asm volatile("s_waitcnt vmcnt(0)" ::: "memory");
    }
    __builtin_amdgcn_s_barrier();      // all waves' tile-t loads visible
    if (k0 <= q0w + 15) {   // wave-uniform: skip tiles fully above this wave's diagonal
      const u16* ks = sh + cur * 4096;
      const u16* vs = sh + 8192 + cur * 4096;
      f32x4 s[4];
      __builtin_amdgcn_s_setprio(1);
#pragma unroll
      for (int kg = 0; kg < 4; ++kg) {
        short8 ka0 = *(const short8*)&ks[(kg * 16 + lr) * 64 + ((lg ^ (lr & 7)) * 8)];
        short8 ka1 = *(const short8*)&ks[(kg * 16 + lr) * 64 + (((4 + lg) ^ (lr & 7)) * 8)];
        f32x4 z = {};
        z = mfma_bf16(ka0, qf0, z);
        z = mfma_bf16(ka1, qf1, z);
        s[kg] = z;
      }
      __builtin_amdgcn_s_setprio(0);
      int qa = q0w + lr;
      bool domask = (k0 + 63 > q0w);
      float sv[16];
      float ps = 0.f;
#pragma unroll
      for (int kg = 0; kg < 4; ++kg)
#pragma unroll
        for (int rr = 0; rr < 4; ++rr) {
          float x = s[kg][rr];
          if (domask) {
            int key = k0 + kg * 16 + 4 * lg + rr;
            x = (key <= qa) ? x : -1e30f;
          }
          float p = __builtin_amdgcn_exp2f(x);   // exp2(-1e30) = 0 for masked
          sv[kg * 4 + rr] = p;
          ps += p;
        }
      ps += __shfl_xor(ps, 16);
      ps += __shfl_xor(ps, 32);
      lrow += ps;
      short8 pb[2];
#pragma unroll
      for (int c = 0; c < 2; ++c) {
        u32x4 uu;
        uu[0] = cvt_pk_bf16(sv[c * 8 + 0], sv[c * 8 + 1]);
        uu[1] = cvt_pk_bf16(sv[c * 8 + 2], sv[c * 8 + 3]);
        uu[2] = cvt_pk_bf16(sv[c * 8 + 4], sv[c * 8 + 5]);
        uu[3] = cvt_pk_bf16(sv[c * 8 + 6], sv[c * 8 + 7]);
        pb[c] = __builtin_bit_cast(short8, uu);
      }
      __builtin_amdgcn_s_setprio(1);
#pragma unroll
      for (int dt = 0; dt < 4; ++dt) {
        short8 va0 = *(const short8*)&vs[(dt * 16 + lr) * 64 + ((lg ^ (lr & 7)) * 8)];
        short8 va1 = *(const short8*)&vs[(dt * 16 + lr) * 64 + (((4 + lg) ^ (lr & 7)) * 8)];
        ao[dt] = mfma_bf16(va0, pb[0], ao[dt]);
        ao[dt] = mfma_bf16(va1, pb[1], ao[dt]);
      }
      __builtin_amdgcn_s_setprio(0);
    }
    __builtin_amdgcn_s_barrier();      // all waves done reading buf cur
  }

  // epilogue: O^T(d,q) -> O(q,d) via per-wave padded LDS (reuse sh)
  u16* ow = sh + w * 1152;   // [16][72]
  float inv = 1.0f / lrow;
#pragma unroll
  for (int dt = 0; dt < 4; ++dt) {
    u32x2 pk;
    pk[0] = cvt_pk_bf16(ao[dt][0] * inv, ao[dt][1] * inv);
    pk[1] = cvt_pk_bf16(ao[dt][2] * inv, ao[dt][3] * inv);
    *(u32x2*)&ow[lr * 72 + dt * 16 + 4 * lg] = pk;
  }
  __syncthreads();
  int r = l >> 2, hc = l & 3;
  const u16* srow = sh + w * 1152 + r * 72 + hc * 16;
  u16* dst = O + ((size_t)(b * T_ + q0w + r)) * 768 + h * 64 + hc * 16;
  *(uint4*)&dst[0] = *(const uint4*)&srow[0];
  *(uint4*)&dst[8] = *(const uint4*)&srow[8];
}

// ---------------- launch ----------------

extern "C" void kernel_launch(void* const* d_in, const int* in_sizes, int n_in,
                              void* d_out, int out_size, void* d_ws, size_t ws_size,
                              hipStream_t stream) {
  const float* x     = (const float*)d_in[0];
  const float* Wqkv  = (const float*)d_in[1];
  const float* bqkv  = (const float*)d_in[2];
  const float* Wproj = (const float*)d_in[3];
  const float* bproj = (const float*)d_in[4];
  float* out = (float*)d_out;
  char* ws = (char*)d_ws;
  u16* xb     = (u16*)(ws);                // 4096*768*2      = 6291456
  u16* wqkvT  = (u16*)(ws + 6291456);      // 2304*768*2      = 3538944
  u16* wprojT = (u16*)(ws + 9830400);      // 768*768*2       = 1179648
  u16* qb     = (u16*)(ws + 11010048);     // 24*2048*64*2    = 6291456
  u16* kb     = (u16*)(ws + 17301504);     // 6291456
  u16* vpb    = (u16*)(ws + 23592960);     // 6291456
  u16* ob     = (u16*)(ws + 29884416);     // 6291456  (total 36175872)

  prep_kernel<<<5376, 256, 0, stream>>>(x, Wqkv, Wproj, xb, wqkvT, wprojT);
  gemm_kernel<0, 128><<<dim3(18, 32), 256, 0, stream>>>(xb, wqkvT, bqkv, qb, kb, vpb, nullptr);
  attn_kernel<<<768, 256, 0, stream>>>(qb, kb, vpb, ob);
  gemm_kernel<1, 64><<<dim3(6, 64), 256, 0, stream>>>(ob, wprojT, bproj, nullptr, nullptr, nullptr, out);
}

// Round 8
// 86.275 us; speedup vs baseline: 1.1967x; 1.1967x over previous
//
#include <hip/hip_runtime.h>
#include <stdint.h>

typedef short short8 __attribute__((ext_vector_type(8)));
typedef short short4v __attribute__((ext_vector_type(4)));
typedef float f32x4 __attribute__((ext_vector_type(4)));
typedef unsigned int u32x2 __attribute__((ext_vector_type(2)));
typedef unsigned int u32x4 __attribute__((ext_vector_type(4)));
typedef unsigned short u16;
typedef unsigned int u32;

#define T_ 2048
#define QK_SCALE 0.180336878f   // 0.125 * log2(e): softmax in log2 domain

__device__ inline u16 f2bf(float f) {
  unsigned u = __builtin_bit_cast(unsigned, f);
  u += 0x7fffu + ((u >> 16) & 1u);   // RNE; inputs finite
  return (u16)(u >> 16);
}

__device__ inline u32 cvt_pk_bf16(float lo, float hi) {
  u32 r;
  asm("v_cvt_pk_bf16_f32 %0, %1, %2" : "=v"(r) : "v"(lo), "v"(hi));
  return r;
}

__device__ inline f32x4 mfma_bf16(short8 a, short8 b, f32x4 c) {
  return __builtin_amdgcn_mfma_f32_16x16x32_bf16(a, b, c, 0, 0, 0);
}

// async global->LDS, 16B per lane; lds base must be wave-uniform
__device__ inline void gload16(const u16* g, u16* l) {
  __builtin_amdgcn_global_load_lds(
      (const __attribute__((address_space(1))) void*)g,
      (__attribute__((address_space(3))) void*)l, 16, 0, 0);
}

// ---------------- fused prep: convert x + transpose-convert both weights ----------------

__device__ inline void tile_transpose(const float* __restrict__ W, u16* __restrict__ Wt,
                                      int R, int Ccols, int c0, int r0, int t,
                                      float (*tile)[33]) {
  int tr = t >> 3, tc = (t & 7) * 4;
  float4 v = *(const float4*)&W[(size_t)(r0 + tr) * Ccols + c0 + tc];
  tile[tr][tc + 0] = v.x; tile[tr][tc + 1] = v.y;
  tile[tr][tc + 2] = v.z; tile[tr][tc + 3] = v.w;
  __syncthreads();
  short4v o;
#pragma unroll
  for (int i = 0; i < 4; ++i) o[i] = (short)f2bf(tile[tc + i][tr]);
  *(short4v*)&Wt[(size_t)(c0 + tr) * R + r0 + tc] = o;
}

__global__ __launch_bounds__(256) void prep_kernel(const float* __restrict__ x,
                                                   const float* __restrict__ Wqkv,
                                                   const float* __restrict__ Wproj,
                                                   u16* __restrict__ xb,
                                                   u16* __restrict__ wqkvT,
                                                   u16* __restrict__ wprojT) {
  __shared__ float tile[32][33];
  int bid = blockIdx.x, t = threadIdx.x;
  if (bid < 3072) {
    int i = (bid * 256 + t) * 4;
    float4 v = *(const float4*)&x[i];
    short4v o;
    o[0] = (short)f2bf(v.x); o[1] = (short)f2bf(v.y);
    o[2] = (short)f2bf(v.z); o[3] = (short)f2bf(v.w);
    *(short4v*)&xb[i] = o;
  } else if (bid < 3072 + 1728) {
    int t2 = bid - 3072;
    tile_transpose(Wqkv, wqkvT, 768, 2304, (t2 % 72) * 32, (t2 / 72) * 32, t, tile);
  } else {
    int t3 = bid - 4800;
    tile_transpose(Wproj, wprojT, 768, 768, (t3 % 24) * 32, (t3 / 24) * 32, t, tile);
  }
}

// ---------------- MTILE x 128 GEMM (gload_lds w16 + XOR swizzle + XCD chunking) ----------------
// A [M][768] bf16, Bt [N][768] bf16 (n-major). 4 waves.
// MODE 0: qkv epilogue (q/k direct, V^T via LDS transpose);
// MODE 1: proj epilogue (fp32 out + bias).

template <int MODE, int MTILE>
__global__ __launch_bounds__(256) void gemm_kernel(const u16* __restrict__ A,
                                                   const u16* __restrict__ Bt,
                                                   const float* __restrict__ bias,
                                                   u16* __restrict__ qb,
                                                   u16* __restrict__ kb,
                                                   u16* __restrict__ vpb,
                                                   float* __restrict__ out) {
  constexpr int MF = MTILE / 32;            // m-fragments per wave
  __shared__ u16 S[MTILE * 64 + 8192];      // As | Bs (reused as transpose buf)
  u16* As = S;
  u16* Bs = S + MTILE * 64;
  int tid = threadIdx.x, w = tid >> 6, l = tid & 63, lg = l >> 4, lr = l & 15;
  // XCD-chunked bijective swizzle: consecutive logical ids (same A panel) on one XCD
  int nwg = gridDim.x * gridDim.y;
  int hw = blockIdx.y * gridDim.x + blockIdx.x;
  int logical = (hw & 7) * (nwg >> 3) + (hw >> 3);
  int n0 = (logical % gridDim.x) * 128, m0 = (logical / gridDim.x) * MTILE;
  int wm = (w >> 1) * (MTILE / 2), wn = (w & 1) * 64;
  f32x4 acc[MF][4] = {};
  int rsub = l >> 3;
  int sc = ((l & 7) ^ rsub) * 8;
  for (int kt = 0; kt < 12; ++kt) {
    int k0 = kt * 64;
    __syncthreads();
#pragma unroll
    for (int j = 0; j < MF; ++j) {
      int row = w * (MTILE / 4) + j * 8 + rsub;
      gload16(&A[(size_t)(m0 + row) * 768 + k0 + sc], &As[(w * MF + j) * 512]);
    }
#pragma unroll
    for (int j = 0; j < 4; ++j) {
      int row = w * 32 + j * 8 + rsub;
      gload16(&Bt[(size_t)(n0 + row) * 768 + k0 + sc], &Bs[(w * 4 + j) * 512]);
    }
    __syncthreads();
    short8 a[MF][2], b[4][2];
#pragma unroll
    for (int h = 0; h < 2; ++h) {
#pragma unroll
      for (int mf = 0; mf < MF; ++mf) {
        int cw = ((h * 4 + lg) ^ (lr & 7)) * 8;
        a[mf][h] = *(const short8*)&As[(wm + mf * 16 + lr) * 64 + cw];
      }
#pragma unroll
      for (int nf = 0; nf < 4; ++nf) {
        int cw = ((h * 4 + lg) ^ (lr & 7)) * 8;
        b[nf][h] = *(const short8*)&Bs[(wn + nf * 16 + lr) * 64 + cw];
      }
    }
#pragma unroll
    for (int h = 0; h < 2; ++h)
#pragma unroll
      for (int mf = 0; mf < MF; ++mf)
#pragma unroll
        for (int nf = 0; nf < 4; ++nf)
          acc[mf][nf] = mfma_bf16(a[mf][h], b[nf][h], acc[mf][nf]);
  }

  if constexpr (MODE == 0) {
    int sec = (n0 >= 1536) ? 2 : (n0 >= 768 ? 1 : 0);
    int ncol0 = n0 - sec * 768;
    if (sec < 2) {
#pragma unroll
      for (int nf = 0; nf < 4; ++nf) {
        int nn = wn + nf * 16 + lr;
        float bv = bias[n0 + nn];
        int c = ncol0 + nn;
        int hh = c >> 6, d = c & 63;
#pragma unroll
        for (int mf = 0; mf < MF; ++mf)
#pragma unroll
          for (int rr = 0; rr < 4; ++rr) {
            int m = m0 + wm + mf * 16 + 4 * lg + rr;
            int bb = m >> 11, tt = m & 2047;
            int bh = bb * 12 + hh;
            float v = acc[mf][nf][rr] + bv;
            if (sec == 0) qb[((size_t)bh * T_ + tt) * 64 + d] = f2bf(v * QK_SCALE);
            else          kb[((size_t)bh * T_ + tt) * 64 + d] = f2bf(v);
          }
      }
    } else {
      // V^T: transpose in LDS (p5 key-permutation folded into column), coalesced rows out.
      __syncthreads();   // done reading As/Bs
#pragma unroll
      for (int nf = 0; nf < 4; ++nf) {
        int row = wn + nf * 16 + lr;          // n-index within block (d dim), [0,128)
        float bv = bias[n0 + row];
        int swz = (row & 7) << 3;             // u16-granule XOR (16B chunks)
#pragma unroll
        for (int mf = 0; mf < MF; ++mf) {
          // permuted m-col: p5 = 8*lg + 4*hi + j within each 32-token group
          int pcol0 = wm + (mf >> 1) * 32 + 8 * lg + 4 * (mf & 1);
          u32x2 pk;
          pk[0] = cvt_pk_bf16(acc[mf][nf][0] + bv, acc[mf][nf][1] + bv);
          pk[1] = cvt_pk_bf16(acc[mf][nf][2] + bv, acc[mf][nf][3] + bv);
          *(u32x2*)&S[row * MTILE + (pcol0 ^ swz)] = pk;
        }
      }
      __syncthreads();
      constexpr int CPT = MTILE / 2;          // cols per thread (2 threads/row, 128 rows)
      int rowo = tid >> 1, half = tid & 1;
      int c = ncol0 + rowo;
      int d = c & 63, hh = c >> 6;
      int bh = (m0 >> 11) * 12 + hh;
      u16* dst = vpb + ((size_t)bh * 64 + d) * T_ + (m0 & 2047) + half * CPT;
      int swzo = (rowo & 7) << 3;
#pragma unroll
      for (int i = 0; i < CPT / 8; ++i) {
        int col = half * CPT + i * 8;
        uint4 v = *(const uint4*)&S[rowo * MTILE + (col ^ swzo)];
        *(uint4*)&dst[i * 8] = v;
      }
    }
  } else {
#pragma unroll
    for (int nf = 0; nf < 4; ++nf) {
      int n = n0 + wn + nf * 16 + lr;
      float bv = bias[n];
#pragma unroll
      for (int mf = 0; mf < MF; ++mf)
#pragma unroll
        for (int rr = 0; rr < 4; ++rr) {
          int m = m0 + wm + mf * 16 + 4 * lg + rr;
          out[(size_t)m * 768 + n] = acc[mf][nf][rr] + bv;
        }
    }
  }
}

// ---------------- flash attention (no-max softmax, 4 waves x 16 q, 64-q blocks) ----------------
// R6-proven structure: __syncthreads() loop (no inline vmcnt), setprio around MFMA.
// Q,K: [BH][T][64] bf16 (Q pre-scaled by 0.125*log2e), Vp: [BH][64][T] bf16
// (key-permuted), O: [B*T][768] bf16. Grid: 24 heads x 32 q-blocks = 768 blocks.

__global__ __launch_bounds__(256) void attn_kernel(const u16* __restrict__ Q,
                                                   const u16* __restrict__ K,
                                                   const u16* __restrict__ Vp,
                                                   u16* __restrict__ O) {
  __shared__ u16 sh[16384];  // K dbuf 2x4096, V dbuf 2x4096 (swizzled linear)
  int tid = threadIdx.x;
  int w = tid >> 6, l = tid & 63, lg = l >> 4, lr = l & 15;
  int idx = blockIdx.x;
  int head = idx % 24;                 // 24 % 8 == 0: same head -> same XCD (L2 reuse)
  int qblk = 31 - idx / 24;            // big-work blocks dispatch first
  int b = head / 12, h = head % 12;
  int q0 = qblk * 64;
  int q0w = q0 + w * 16;               // this wave's 16 q-rows
  const u16* Qb = Q + (size_t)head * T_ * 64;
  const u16* Kb = K + (size_t)head * T_ * 64;
  const u16* Vb = Vp + (size_t)head * 64 * T_;

  short8 qf0 = *(const short8*)&Qb[(size_t)(q0w + lr) * 64 + 8 * lg];
  short8 qf1 = *(const short8*)&Qb[(size_t)(q0w + lr) * 64 + 32 + 8 * lg];

  f32x4 ao[4] = {};
  float lrow = 0.f;
  int rsub = l >> 3;
  int scs = ((l & 7) ^ rsub) * 8;
  const int nt = qblk + 1;             // 64-key tiles covering keys <= q0+63

  // prologue: stage tile 0 (4 waves x 2 issues cover 64 rows of K and V)
#pragma unroll
  for (int j = 0; j < 2; ++j) {
    int ci = w * 2 + j;
    int row = ci * 8 + rsub;
    gload16(&Kb[(size_t)row * 64 + scs], &sh[ci * 512]);
    gload16(&Vb[(size_t)row * T_ + scs], &sh[8192 + ci * 512]);
  }
  __syncthreads();

  for (int t = 0; t < nt; ++t) {
    int cur = t & 1;
    int k0 = t * 64;
    if (t + 1 < nt) {
      int k1 = k0 + 64;
#pragma unroll
      for (int j = 0; j < 2; ++j) {
        int ci = w * 2 + j;
        int row = ci * 8 + rsub;
        gload16(&Kb[(size_t)(k1 + row) * 64 + scs], &sh[(cur ^ 1) * 4096 + ci * 512]);
        gload16(&Vb[(size_t)row * T_ + k1 + scs], &sh[8192 + (cur ^ 1) * 4096 + ci * 512]);
      }
    }
    if (k0 <= q0w + 15) {   // wave-uniform: skip tiles fully above this wave's diagonal
      const u16* ks = sh + cur * 4096;
      const u16* vs = sh + 8192 + cur * 4096;
      f32x4 s[4];
      __builtin_amdgcn_s_setprio(1);
#pragma unroll
      for (int kg = 0; kg < 4; ++kg) {
        short8 ka0 = *(const short8*)&ks[(kg * 16 + lr) * 64 + ((lg ^ (lr & 7)) * 8)];
        short8 ka1 = *(const short8*)&ks[(kg * 16 + lr) * 64 + (((4 + lg) ^ (lr & 7)) * 8)];
        f32x4 z = {};
        z = mfma_bf16(ka0, qf0, z);
        z = mfma_bf16(ka1, qf1, z);
        s[kg] = z;
      }
      __builtin_amdgcn_s_setprio(0);
      int qa = q0w + lr;
      bool domask = (k0 + 63 > q0w);
      float sv[16];
      float ps = 0.f;
#pragma unroll
      for (int kg = 0; kg < 4; ++kg)
#pragma unroll
        for (int rr = 0; rr < 4; ++rr) {
          float x = s[kg][rr];
          if (domask) {
            int key = k0 + kg * 16 + 4 * lg + rr;
            x = (key <= qa) ? x : -1e30f;
          }
          float p = __builtin_amdgcn_exp2f(x);   // exp2(-1e30) = 0 for masked
          sv[kg * 4 + rr] = p;
          ps += p;
        }
      ps += __shfl_xor(ps, 16);
      ps += __shfl_xor(ps, 32);
      lrow += ps;
      short8 pb[2];
#pragma unroll
      for (int c = 0; c < 2; ++c) {
        u32x4 uu;
        uu[0] = cvt_pk_bf16(sv[c * 8 + 0], sv[c * 8 + 1]);
        uu[1] = cvt_pk_bf16(sv[c * 8 + 2], sv[c * 8 + 3]);
        uu[2] = cvt_pk_bf16(sv[c * 8 + 4], sv[c * 8 + 5]);
        uu[3] = cvt_pk_bf16(sv[c * 8 + 6], sv[c * 8 + 7]);
        pb[c] = __builtin_bit_cast(short8, uu);
      }
      __builtin_amdgcn_s_setprio(1);
#pragma unroll
      for (int dt = 0; dt < 4; ++dt) {
        short8 va0 = *(const short8*)&vs[(dt * 16 + lr) * 64 + ((lg ^ (lr & 7)) * 8)];
        short8 va1 = *(const short8*)&vs[(dt * 16 + lr) * 64 + (((4 + lg) ^ (lr & 7)) * 8)];
        ao[dt] = mfma_bf16(va0, pb[0], ao[dt]);
        ao[dt] = mfma_bf16(va1, pb[1], ao[dt]);
      }
      __builtin_amdgcn_s_setprio(0);
    }
    __syncthreads();
  }

  // epilogue: O^T(d,q) -> O(q,d) via per-wave padded LDS (reuse sh)
  u16* ow = sh + w * 1152;   // [16][72]
  float inv = 1.0f / lrow;
#pragma unroll
  for (int dt = 0; dt < 4; ++dt) {
    u32x2 pk;
    pk[0] = cvt_pk_bf16(ao[dt][0] * inv, ao[dt][1] * inv);
    pk[1] = cvt_pk_bf16(ao[dt][2] * inv, ao[dt][3] * inv);
    *(u32x2*)&ow[lr * 72 + dt * 16 + 4 * lg] = pk;
  }
  __syncthreads();
  int r = l >> 2, hc = l & 3;
  const u16* srow = sh + w * 1152 + r * 72 + hc * 16;
  u16* dst = O + ((size_t)(b * T_ + q0w + r)) * 768 + h * 64 + hc * 16;
  *(uint4*)&dst[0] = *(const uint4*)&srow[0];
  *(uint4*)&dst[8] = *(const uint4*)&srow[8];
}

// ---------------- launch ----------------

extern "C" void kernel_launch(void* const* d_in, const int* in_sizes, int n_in,
                              void* d_out, int out_size, void* d_ws, size_t ws_size,
                              hipStream_t stream) {
  const float* x     = (const float*)d_in[0];
  const float* Wqkv  = (const float*)d_in[1];
  const float* bqkv  = (const float*)d_in[2];
  const float* Wproj = (const float*)d_in[3];
  const float* bproj = (const float*)d_in[4];
  float* out = (float*)d_out;
  char* ws = (char*)d_ws;
  u16* xb     = (u16*)(ws);                // 4096*768*2      = 6291456
  u16* wqkvT  = (u16*)(ws + 6291456);      // 2304*768*2      = 3538944
  u16* wprojT = (u16*)(ws + 9830400);      // 768*768*2       = 1179648
  u16* qb     = (u16*)(ws + 11010048);     // 24*2048*64*2    = 6291456
  u16* kb     = (u16*)(ws + 17301504);     // 6291456
  u16* vpb    = (u16*)(ws + 23592960);     // 6291456
  u16* ob     = (u16*)(ws + 29884416);     // 6291456  (total 36175872)

  prep_kernel<<<5376, 256, 0, stream>>>(x, Wqkv, Wproj, xb, wqkvT, wprojT);
  gemm_kernel<0, 64><<<dim3(18, 64), 256, 0, stream>>>(xb, wqkvT, bqkv, qb, kb, vpb, nullptr);
  attn_kernel<<<768, 256, 0, stream>>>(qb, kb, vpb, ob);
  gemm_kernel<1, 64><<<dim3(6, 64), 256, 0, stream>>>(ob, wprojT, bproj, nullptr, nullptr, nullptr, out);
}